// Round 5
// baseline (266.236 us; speedup 1.0000x reference)
//
#include <hip/hip_runtime.h>

#define LL 1024
#define DD 512
#define HH 8
#define EE 64
#define LDX (LL*DD)
#define BB 16

typedef _Float16 h8 __attribute__((ext_vector_type(8)));
typedef _Float16 h4 __attribute__((ext_vector_type(4)));
typedef float f4 __attribute__((ext_vector_type(4)));
typedef int i4 __attribute__((ext_vector_type(4)));

__device__ __forceinline__ f4 mfma16(h8 a, h8 b, f4 c) {
    return __builtin_amdgcn_mfma_f32_16x16x32_f16(a, b, c, 0, 0, 0);
}

__device__ __forceinline__ h8 pack8(f4 a, f4 b) {
    h8 o;
    #pragma unroll
    for (int j = 0; j < 4; ++j) { o[j] = (_Float16)a[j]; o[4+j] = (_Float16)b[j]; }
    return o;
}

// ---------------- P: prep (x16 pass eliminated; qkv reads x directly) ----
// bx < 2048        : x -> xT16[s][b] (gather table)
// bx < 2048+192    : Wq/Wk/Wv -> WT (B-frag layout, q scale*log2e baked)
// else             : Wo -> f16
__global__ __launch_bounds__(256) void k_prep_all(
    const float* __restrict__ x,  const float* __restrict__ Wq,
    const float* __restrict__ Wk, const float* __restrict__ Wv,
    const float* __restrict__ Wo,
    _Float16* __restrict__ xT, _Float16* __restrict__ WT,
    _Float16* __restrict__ Wo16)
{
    const int bx = blockIdx.x;
    const int t = threadIdx.x;
    if (bx < 2048) {
        const int s = bx * 256 + t;
        h8 lo, hi;
        #pragma unroll
        for (int b = 0; b < 8; ++b)  lo[b] = (_Float16)x[(size_t)b*LDX + s];
        #pragma unroll
        for (int b = 0; b < 8; ++b)  hi[b] = (_Float16)x[(size_t)(b+8)*LDX + s];
        _Float16* d = xT + (size_t)s * BB;
        *(h8*)d = lo; *(h8*)(d + 8) = hi;
    } else if (bx < 2048 + 192) {
        const int id = bx - 2048;
        const int d0 = (id & 7) * 64;
        const int zz = id >> 3;
        const float* src; float sc = 1.f;
        if (zz < 8)       src = Wk + (size_t)zz*DD*EE;
        else if (zz < 16) src = Wv + (size_t)(zz-8)*DD*EE;
        else            { src = Wq + (size_t)(zz-16)*DD*EE; sc = 0.18033688011112042f; }
        const int e = t & 63, dq = t >> 6;
        #pragma unroll
        for (int i = 0; i < 16; ++i) {
            int d = d0 + dq*16 + i;
            WT[(size_t)(zz*64 + e)*DD + d] = (_Float16)(src[(size_t)d*EE + e] * sc);
        }
    } else {
        const int i = (bx - (2048 + 192)) * 256 + t;
        f4 v = ((const f4*)Wo)[i];
        #pragma unroll
        for (int j = 0; j < 4; ++j) Wo16[4*i + j] = (_Float16)v[j];
    }
}

// ---------------- qkv tile body (M128xN128, fp32 A-input) ----------------
__device__ __forceinline__ void qkv_body(
    int y, int r0,
    const float* __restrict__ x, const _Float16* __restrict__ WT,
    _Float16* __restrict__ qw, _Float16* __restrict__ kw, _Float16* __restrict__ vw,
    _Float16* smem)
{
    auto As = (_Float16(*)[128][72])smem;                 // [2][128][72]
    auto Bs = (_Float16(*)[128][72])(smem + 2*128*72);    // [2][128][72]

    const int t = threadIdx.x;
    const int wv = t >> 6, lane = t & 63;
    const int m = lane & 15, qd = lane >> 4;
    const int sr = t >> 1, sc0 = (t & 1) * 32;

    const float*    ax = x  + (size_t)(r0 + sr)*DD + sc0;
    const _Float16* bx = WT + (size_t)(y*128 + sr)*DD + sc0;

    #pragma unroll
    for (int c = 0; c < 4; ++c) {
        f4 u = *(const f4*)(ax + 8*c);
        f4 w = *(const f4*)(ax + 8*c + 4);
        *(h8*)&As[0][sr][sc0 + 8*c] = pack8(u, w);
        *(h8*)&Bs[0][sr][sc0 + 8*c] = *(const h8*)(bx + 8*c);
    }
    __syncthreads();

    f4 acc[2][8] = {};
    int cur = 0;
    for (int kt = 0; kt < 8; ++kt) {
        const int alt = cur ^ 1;
        f4 an[8]; h8 bn[4];
        if (kt < 7) {
            const float*    a2 = ax + (kt+1)*64;
            const _Float16* b2 = bx + (kt+1)*64;
            #pragma unroll
            for (int c = 0; c < 4; ++c) {
                an[2*c]   = *(const f4*)(a2 + 8*c);
                an[2*c+1] = *(const f4*)(a2 + 8*c + 4);
                bn[c]     = *(const h8*)(b2 + 8*c);
            }
        }
        #pragma unroll
        for (int ks = 0; ks < 2; ++ks) {
            h8 a0 = *(const h8*)&As[cur][32*wv +  0 + m][32*ks + 8*qd];
            h8 a1 = *(const h8*)&As[cur][32*wv + 16 + m][32*ks + 8*qd];
            #pragma unroll
            for (int nt = 0; nt < 8; ++nt) {
                h8 bb = *(const h8*)&Bs[cur][16*nt + m][32*ks + 8*qd];
                acc[0][nt] = mfma16(a0, bb, acc[0][nt]);
                acc[1][nt] = mfma16(a1, bb, acc[1][nt]);
            }
        }
        if (kt < 7) {
            #pragma unroll
            for (int c = 0; c < 4; ++c) {
                *(h8*)&As[alt][sr][sc0 + 8*c] = pack8(an[2*c], an[2*c+1]);
                *(h8*)&Bs[alt][sr][sc0 + 8*c] = bn[c];
            }
            __syncthreads();
            cur = alt;
        }
    }

    #pragma unroll
    for (int nt = 0; nt < 8; ++nt) {
        const int n = y*128 + 16*nt + m;
        const int z = n >> 6, e = n & 63;
        if (z >= 17) continue;
        _Float16* dst; int h;
        if (z < 8)       { dst = kw; h = z; }
        else if (z < 16) { dst = vw; h = z - 8; }
        else             { dst = qw; h = 0; }
        dst += (size_t)h*LL*EE + e;
        #pragma unroll
        for (int mt = 0; mt < 2; ++mt)
            #pragma unroll
            for (int r = 0; r < 4; ++r) {
                int R = r0 + 32*wv + 16*mt + 4*qd + r;
                int b = R >> 10, l = R & 1023;
                dst[((size_t)b*HH*LL + l)*EE] = (_Float16)acc[mt][nt][r];
            }
    }
}

// ---------------- qshuf tile body (depth-3 register pipeline) ------------
__device__ __forceinline__ void qshuf_body(
    int l0, int h,
    const _Float16* __restrict__ xT, const int* __restrict__ perms,
    const _Float16* __restrict__ WT, _Float16* __restrict__ qw,
    _Float16* smem)
{
    auto As = (_Float16(*)[64][72])smem;                 // [2][64][72]
    auto Bs = (_Float16(*)[64][72])(smem + 2*64*72);     // [2][64][72]

    const _Float16* Wb = WT + (size_t)((16 + h)*64)*DD;
    const int* pbase = perms + (size_t)(h-1)*LDX;

    const int t = threadIdx.x;
    const int wv = t >> 6, lane = t & 63;
    const int m = lane & 15, qd = lane >> 4;
    const int lg = t >> 6, kcol = t & 63;
    const int br = t >> 2, bc0 = (t & 3) * 16;

    int pv[8];
    #pragma unroll
    for (int kt = 0; kt < 8; ++kt)
        pv[kt] = pbase[(size_t)(l0 + lg)*DD + kt*64 + kcol];

    h8 g0p[3], g1p[3], b0p[3], b1p[3];
    #pragma unroll
    for (int j = 0; j < 3; ++j) {
        const _Float16* g = xT + (size_t)pv[j] * BB;
        g0p[j] = *(const h8*)g; g1p[j] = *(const h8*)(g + 8);
        const _Float16* s = Wb + (size_t)br*DD + j*64 + bc0;
        b0p[j] = *(const h8*)s; b1p[j] = *(const h8*)(s + 8);
    }

    *(h8*)&Bs[0][br][bc0]     = b0p[0];
    *(h8*)&Bs[0][br][bc0 + 8] = b1p[0];
    #pragma unroll
    for (int i = 0; i < 8; ++i) As[0][lg*16 + i][kcol]     = g0p[0][i];
    #pragma unroll
    for (int i = 0; i < 8; ++i) As[0][lg*16 + 8 + i][kcol] = g1p[0][i];
    __syncthreads();

    f4 acc[4] = {};
    #pragma unroll
    for (int kt = 0; kt < 8; ++kt) {
        const int cur = kt & 1;
        if (kt + 3 < 8) {
            const int st = (kt + 3) % 3;
            const _Float16* g = xT + (size_t)pv[kt+3] * BB;
            g0p[st] = *(const h8*)g; g1p[st] = *(const h8*)(g + 8);
            const _Float16* s = Wb + (size_t)br*DD + (kt+3)*64 + bc0;
            b0p[st] = *(const h8*)s; b1p[st] = *(const h8*)(s + 8);
        }
        #pragma unroll
        for (int ks = 0; ks < 2; ++ks) {
            h8 a = *(const h8*)&As[cur][16*wv + m][32*ks + 8*qd];
            #pragma unroll
            for (int nt = 0; nt < 4; ++nt) {
                h8 bb = *(const h8*)&Bs[cur][16*nt + m][32*ks + 8*qd];
                acc[nt] = mfma16(a, bb, acc[nt]);
            }
        }
        if (kt < 7) {
            const int alt = cur ^ 1;
            const int st = (kt + 1) % 3;
            *(h8*)&Bs[alt][br][bc0]     = b0p[st];
            *(h8*)&Bs[alt][br][bc0 + 8] = b1p[st];
            #pragma unroll
            for (int i = 0; i < 8; ++i) As[alt][lg*16 + i][kcol]     = g0p[st][i];
            #pragma unroll
            for (int i = 0; i < 8; ++i) As[alt][lg*16 + 8 + i][kcol] = g1p[st][i];
            __syncthreads();
        }
    }

    #pragma unroll
    for (int nt = 0; nt < 4; ++nt)
        #pragma unroll
        for (int r = 0; r < 4; ++r) {
            int b = 4*qd + r;
            qw[((size_t)(b*HH + h)*LL + l0 + wv)*EE + 16*nt + m] = (_Float16)acc[nt][r];
        }
}

// ---------------- K1: fused qkv + qshuf, XCD-aware swizzle ---------------
__global__ __launch_bounds__(256) void k_qkv_qshuf(
    const float* __restrict__ x, const _Float16* __restrict__ xT,
    const int* __restrict__ perms, const _Float16* __restrict__ WT,
    _Float16* __restrict__ qw, _Float16* __restrict__ kw, _Float16* __restrict__ vw)
{
    __shared__ __align__(16) _Float16 smem[4*128*72];   // 73728 B
    const int bx = blockIdx.x;
    const int lx = (bx & 7) * 368 + (bx >> 3);          // XCD-contiguous logical id
    const int g = lx / 23, pos = lx % 23;
    if (pos < 9) {
        const int qid = g*9 + pos;            // [0,1152)
        qkv_body(qid % 9, (qid / 9) * 128, x, WT, qw, kw, vw, smem);
    } else {
        const int sid = g*14 + (pos - 9);     // [0,1792)
        qshuf_body((sid & 255) * 4, (sid >> 8) + 1, xT, perms, WT, qw, smem);
    }
}

// ---------------- K3: attention v7 — QBLK=256, 8 waves -------------------
// attn is staging/L2-bound, not MFMA-bound (MFMA floor ~5us). QBLK 128->256:
// per-block K/V staging shared by 2x threads (K: 1 h8/thread, V: 8 scalar
// LDS writes/thread - both halved), K/V L2 re-reads halved (4 blocks/bh).
// 512 blocks x 2/CU = one full round, 16 waves/CU unchanged.
// setprio around MFMA clusters (T5). In-register softmax as v6.
__global__ __launch_bounds__(512, 2) void k_attn(
    const _Float16* __restrict__ qw, const _Float16* __restrict__ kw,
    const _Float16* __restrict__ vw, _Float16* __restrict__ oa)
{
    const int bh = blockIdx.x;
    const int l0 = blockIdx.y * 256;
    const int b = bh >> 3, h = bh & 7;
    const _Float16* qb = qw + ((size_t)bh*LL + l0)*EE;
    const _Float16* kb = kw + (size_t)bh*LL*EE;
    const _Float16* vb = vw + (size_t)bh*LL*EE;

    __shared__ __align__(16) _Float16 KsF[2][64*64];
    __shared__ __align__(16) _Float16 VtsF[2][64*64];

    const int t = threadIdx.x;
    const int wv = t >> 6, lane = t & 63;
    const int m = lane & 15, qd = lane >> 4;
    const int m7 = m & 7;
    const int qdp = ((qd & 1) << 1) | (qd >> 1);   // chunk perm from permlane build
    const int krow = t >> 3, c0 = t & 7;           // K staging: 1 h8/thread
    const int vkey = t & 63, vec = t >> 6;         // V staging: vec in 0..7
    const int vhi = vkey >> 3, vlo = vkey & 7;

    h8 qa[2][2];
    #pragma unroll
    for (int mt = 0; mt < 2; ++mt)
        #pragma unroll
        for (int ks = 0; ks < 2; ++ks)
            qa[mt][ks] = *(const h8*)(qb + (size_t)(32*wv + 16*mt + m)*EE + 32*ks + 8*qd);

    f4 oacc[2][4] = {};
    f4 lpacc[2] = {};
    h8 ones;
    #pragma unroll
    for (int i = 0; i < 8; ++i) ones[i] = (_Float16)1.f;

    {   // stage kt=0 into buf 0
        const _Float16* sk = kb + (size_t)krow*EE + 8*c0;
        h8 k0 = *(const h8*)sk;
        const _Float16* sv = vb + (size_t)vkey*EE + 8*vec;
        h8 v0 = *(const h8*)sv;
        *(h8*)&KsF[0][(krow<<6) + 8*(c0 ^ (krow & 7))] = k0;
        #pragma unroll
        for (int i = 0; i < 8; ++i)
            VtsF[0][((8*vec + i)<<6) + 8*(vhi ^ i) + vlo] = v0[i];
    }
    __syncthreads();

    for (int kt = 0; kt < 16; ++kt) {
        const int cur = kt & 1, alt = cur ^ 1;
        h8 kn0, vn0;
        if (kt < 15) {   // prefetch kt+1 into regs
            const _Float16* sk = kb + (size_t)((kt+1)*64 + krow)*EE + 8*c0;
            kn0 = *(const h8*)sk;
            const _Float16* sv = vb + (size_t)((kt+1)*64 + vkey)*EE + 8*vec;
            vn0 = *(const h8*)sv;
        }

        // S^T = K Q^T
        f4 sacc[2][4] = {};
        __builtin_amdgcn_s_setprio(1);
        #pragma unroll
        for (int ks = 0; ks < 2; ++ks)
            #pragma unroll
            for (int nt = 0; nt < 4; ++nt) {
                h8 kf = *(const h8*)&KsF[cur][((16*nt + m)<<6) + 8*((4*ks + qd) ^ m7)];
                sacc[0][nt] = mfma16(kf, qa[0][ks], sacc[0][nt]);
                sacc[1][nt] = mfma16(kf, qa[1][ks], sacc[1][nt]);
            }
        __builtin_amdgcn_s_setprio(0);

        // exp2 + pack pairs
        unsigned E[2][4][2];
        #pragma unroll
        for (int mt = 0; mt < 2; ++mt)
            #pragma unroll
            for (int nt = 0; nt < 4; ++nt) {
                float e0 = __builtin_amdgcn_exp2f(sacc[mt][nt][0]);
                float e1 = __builtin_amdgcn_exp2f(sacc[mt][nt][1]);
                float e2 = __builtin_amdgcn_exp2f(sacc[mt][nt][2]);
                float e3 = __builtin_amdgcn_exp2f(sacc[mt][nt][3]);
                E[mt][nt][0] = __builtin_bit_cast(unsigned, __builtin_amdgcn_cvt_pkrtz(e0, e1));
                E[mt][nt][1] = __builtin_bit_cast(unsigned, __builtin_amdgcn_cvt_pkrtz(e2, e3));
            }

        // permlane16_swap builds PV A-fragments in-register
        h8 pa[2][2];
        #pragma unroll
        for (int mt = 0; mt < 2; ++mt)
            #pragma unroll
            for (int ks = 0; ks < 2; ++ks) {
                auto x = __builtin_amdgcn_permlane16_swap(E[mt][2*ks][0], E[mt][2*ks+1][0], false, false);
                auto y = __builtin_amdgcn_permlane16_swap(E[mt][2*ks][1], E[mt][2*ks+1][1], false, false);
                i4 pw;
                pw[0] = (int)x[0]; pw[1] = (int)y[0]; pw[2] = (int)x[1]; pw[3] = (int)y[1];
                pa[mt][ks] = __builtin_bit_cast(h8, pw);
            }

        // O += P V; lp += P * 1 via MFMA
        __builtin_amdgcn_s_setprio(1);
        #pragma unroll
        for (int ks = 0; ks < 2; ++ks) {
            #pragma unroll
            for (int nt = 0; nt < 4; ++nt) {
                h8 vf = *(const h8*)&VtsF[cur][((16*nt + m)<<6) + 8*((4*ks + qdp) ^ m7)];
                oacc[0][nt] = mfma16(pa[0][ks], vf, oacc[0][nt]);
                oacc[1][nt] = mfma16(pa[1][ks], vf, oacc[1][nt]);
            }
            lpacc[0] = mfma16(pa[0][ks], ones, lpacc[0]);
            lpacc[1] = mfma16(pa[1][ks], ones, lpacc[1]);
        }
        __builtin_amdgcn_s_setprio(0);

        if (kt < 15) {   // commit prefetched tile to buf alt, then barrier
            *(h8*)&KsF[alt][(krow<<6) + 8*(c0 ^ (krow & 7))] = kn0;
            #pragma unroll
            for (int i = 0; i < 8; ++i)
                VtsF[alt][((8*vec + i)<<6) + 8*(vhi ^ i) + vlo] = vn0[i];
            __syncthreads();
        }
    }

    _Float16* ob = oa + ((size_t)(b*LL + l0))*(HH*EE) + h*EE;
    #pragma unroll
    for (int mt = 0; mt < 2; ++mt)
        #pragma unroll
        for (int r = 0; r < 4; ++r) {
            const float inv = __builtin_amdgcn_rcpf(lpacc[mt][r]);
            #pragma unroll
            for (int nt = 0; nt < 4; ++nt) {
                int row = 32*wv + 16*mt + 4*qd + r;
                ob[(size_t)row*(HH*EE) + 16*nt + m] = (_Float16)(oacc[mt][nt][r] * inv);
            }
        }
}

// ---------------- K4: output projection, XCD-aware swizzle ---------------
__global__ __launch_bounds__(256) void k_oproj(
    const _Float16* __restrict__ oa, const _Float16* __restrict__ Wo16,
    const float* __restrict__ bo, float* __restrict__ out)
{
    const int lid = ((int)blockIdx.x & 7) * 64 + ((int)blockIdx.x >> 3);
    const int y  = lid & 3;
    const int r0 = (lid >> 2) * 128;

    __shared__ __align__(16) _Float16 As[2][128][72];
    __shared__ __align__(16) _Float16 Bs[2][128][72];

    const int t = threadIdx.x;
    const int wv = t >> 6, lane = t & 63;
    const int m = lane & 15, qd = lane >> 4;
    const int sr = t >> 1, sc0 = (t & 1) * 32;

    const _Float16* ax = oa   + (size_t)(r0 + sr)*DD + sc0;
    const _Float16* bx = Wo16 + (size_t)(y*128 + sr)*DD + sc0;

    #pragma unroll
    for (int c = 0; c < 4; ++c) {
        *(h8*)&As[0][sr][sc0 + 8*c] = *(const h8*)(ax + 8*c);
        *(h8*)&Bs[0][sr][sc0 + 8*c] = *(const h8*)(bx + 8*c);
    }
    __syncthreads();

    f4 acc[2][8] = {};
    int cur = 0;
    for (int kt = 0; kt < 8; ++kt) {
        const int alt = cur ^ 1;
        h8 an[4], bn[4];
        if (kt < 7) {
            const _Float16* a2 = ax + (kt+1)*64;
            const _Float16* b2 = bx + (kt+1)*64;
            #pragma unroll
            for (int c = 0; c < 4; ++c) {
                an[c] = *(const h8*)(a2 + 8*c);
                bn[c] = *(const h8*)(b2 + 8*c);
            }
        }
        #pragma unroll
        for (int ks = 0; ks < 2; ++ks) {
            h8 a0 = *(const h8*)&As[cur][32*wv +  0 + m][32*ks + 8*qd];
            h8 a1 = *(const h8*)&As[cur][32*wv + 16 + m][32*ks + 8*qd];
            #pragma unroll
            for (int nt = 0; nt < 8; ++nt) {
                h8 bb = *(const h8*)&Bs[cur][16*nt + m][32*ks + 8*qd];
                acc[0][nt] = mfma16(a0, bb, acc[0][nt]);
                acc[1][nt] = mfma16(a1, bb, acc[1][nt]);
            }
        }
        if (kt < 7) {
            #pragma unroll
            for (int c = 0; c < 4; ++c) {
                *(h8*)&As[alt][sr][sc0 + 8*c] = an[c];
                *(h8*)&Bs[alt][sr][sc0 + 8*c] = bn[c];
            }
            __syncthreads();
            cur = alt;
        }
    }

    #pragma unroll
    for (int nt = 0; nt < 8; ++nt) {
        const int col = y*128 + 16*nt + m;
        const float bias = bo[col];
        #pragma unroll
        for (int mt = 0; mt < 2; ++mt)
            #pragma unroll
            for (int r = 0; r < 4; ++r) {
                int row = 32*wv + 16*mt + 4*qd + r;
                out[(size_t)(r0 + row)*DD + col] = acc[mt][nt][r] + bias;
            }
    }
}

extern "C" void kernel_launch(void* const* d_in, const int* in_sizes, int n_in,
                              void* d_out, int out_size, void* d_ws, size_t ws_size,
                              hipStream_t stream)
{
    const float* x  = (const float*)d_in[0];
    const int*   pm = (const int*)d_in[1];
    const float* Wq = (const float*)d_in[2];
    const float* Wk = (const float*)d_in[3];
    const float* Wv = (const float*)d_in[4];
    const float* Wo = (const float*)d_in[5];
    const float* bo = (const float*)d_in[6];
    float* out = (float*)d_out;

    const size_t QS = (size_t)BB * HH * LL * EE;
    _Float16* q    = (_Float16*)d_ws;
    _Float16* k    = q + QS;
    _Float16* v    = k + QS;
    _Float16* oaw  = v + QS;
    _Float16* xT   = oaw;              // alias: dead before k_attn writes oaw
    _Float16* WT   = oaw + QS;
    _Float16* Wo16 = WT + (size_t)24*64*DD;

    k_prep_all <<<dim3(2048 + 192 + 256), 256, 0, stream>>>(
        x, Wq, Wk, Wv, Wo, xT, WT, Wo16);
    k_qkv_qshuf<<<dim3(2944),          256, 0, stream>>>(x, xT, pm, WT, q, k, v);
    k_attn     <<<dim3(BB*HH, LL/256), 512, 0, stream>>>(q, k, v, oaw);
    k_oproj    <<<dim3(512),           256, 0, stream>>>(oaw, Wo16, bo, out);
}

// Round 6
// 247.756 us; speedup vs baseline: 1.0746x; 1.0746x over previous
//
#include <hip/hip_runtime.h>

#define LL 1024
#define DD 512
#define HH 8
#define EE 64
#define LDX (LL*DD)
#define BB 16

typedef _Float16 h8 __attribute__((ext_vector_type(8)));
typedef _Float16 h4 __attribute__((ext_vector_type(4)));
typedef float f4 __attribute__((ext_vector_type(4)));
typedef int i4 __attribute__((ext_vector_type(4)));

__device__ __forceinline__ f4 mfma16(h8 a, h8 b, f4 c) {
    return __builtin_amdgcn_mfma_f32_16x16x32_f16(a, b, c, 0, 0, 0);
}

// ---------------- P: prep, x read ONCE for both xT and x16 ---------------
// bx < 2048        : x -> xT16[s][b] (gather table) AND x16 (row-major f16)
// bx < 2048+192    : Wq/Wk/Wv -> WT (B-frag layout, q scale*log2e baked)
// else             : Wo -> f16
__global__ __launch_bounds__(256) void k_prep_all(
    const float* __restrict__ x,  const float* __restrict__ Wq,
    const float* __restrict__ Wk, const float* __restrict__ Wv,
    const float* __restrict__ Wo,
    _Float16* __restrict__ xT, _Float16* __restrict__ x16,
    _Float16* __restrict__ WT, _Float16* __restrict__ Wo16)
{
    const int bx = blockIdx.x;
    const int t = threadIdx.x;
    if (bx < 2048) {
        const int s = bx * 256 + t;
        h8 lo, hi;
        #pragma unroll
        for (int b = 0; b < 8; ++b)  lo[b] = (_Float16)x[(size_t)b*LDX + s];
        #pragma unroll
        for (int b = 0; b < 8; ++b)  hi[b] = (_Float16)x[(size_t)(b+8)*LDX + s];
        _Float16* d = xT + (size_t)s * BB;
        *(h8*)d = lo; *(h8*)(d + 8) = hi;
        #pragma unroll
        for (int b = 0; b < 8; ++b)  x16[(size_t)b*LDX + s]     = lo[b];
        #pragma unroll
        for (int b = 0; b < 8; ++b)  x16[(size_t)(b+8)*LDX + s] = hi[b];
    } else if (bx < 2048 + 192) {
        const int id = bx - 2048;
        const int d0 = (id & 7) * 64;
        const int zz = id >> 3;
        const float* src; float sc = 1.f;
        if (zz < 8)       src = Wk + (size_t)zz*DD*EE;
        else if (zz < 16) src = Wv + (size_t)(zz-8)*DD*EE;
        else            { src = Wq + (size_t)(zz-16)*DD*EE; sc = 0.18033688011112042f; }
        const int e = t & 63, dq = t >> 6;
        #pragma unroll
        for (int i = 0; i < 16; ++i) {
            int d = d0 + dq*16 + i;
            WT[(size_t)(zz*64 + e)*DD + d] = (_Float16)(src[(size_t)d*EE + e] * sc);
        }
    } else {
        const int i = (bx - (2048 + 192)) * 256 + t;
        f4 v = ((const f4*)Wo)[i];
        #pragma unroll
        for (int j = 0; j < 4; ++j) Wo16[4*i + j] = (_Float16)v[j];
    }
}

// ---------------- qkv tile body (M128xN128, pipelined, f16 A) ------------
__device__ __forceinline__ void qkv_body(
    int y, int r0,
    const _Float16* __restrict__ x16, const _Float16* __restrict__ WT,
    _Float16* __restrict__ qw, _Float16* __restrict__ kw, _Float16* __restrict__ vw,
    _Float16* smem)
{
    auto As = (_Float16(*)[128][72])smem;                 // [2][128][72]
    auto Bs = (_Float16(*)[128][72])(smem + 2*128*72);    // [2][128][72]

    const int t = threadIdx.x;
    const int wv = t >> 6, lane = t & 63;
    const int m = lane & 15, qd = lane >> 4;
    const int sr = t >> 1, sc0 = (t & 1) * 32;

    const _Float16* ax = x16 + (size_t)(r0 + sr)*DD + sc0;
    const _Float16* bx = WT  + (size_t)(y*128 + sr)*DD + sc0;

    #pragma unroll
    for (int c = 0; c < 4; ++c) {
        *(h8*)&As[0][sr][sc0 + 8*c] = *(const h8*)(ax + 8*c);
        *(h8*)&Bs[0][sr][sc0 + 8*c] = *(const h8*)(bx + 8*c);
    }
    __syncthreads();

    f4 acc[2][8] = {};
    int cur = 0;
    for (int kt = 0; kt < 8; ++kt) {
        const int alt = cur ^ 1;
        h8 an[4], bn[4];
        if (kt < 7) {
            const _Float16* a2 = ax + (kt+1)*64;
            const _Float16* b2 = bx + (kt+1)*64;
            #pragma unroll
            for (int c = 0; c < 4; ++c) {
                an[c] = *(const h8*)(a2 + 8*c);
                bn[c] = *(const h8*)(b2 + 8*c);
            }
        }
        #pragma unroll
        for (int ks = 0; ks < 2; ++ks) {
            h8 a0 = *(const h8*)&As[cur][32*wv +  0 + m][32*ks + 8*qd];
            h8 a1 = *(const h8*)&As[cur][32*wv + 16 + m][32*ks + 8*qd];
            #pragma unroll
            for (int nt = 0; nt < 8; ++nt) {
                h8 bb = *(const h8*)&Bs[cur][16*nt + m][32*ks + 8*qd];
                acc[0][nt] = mfma16(a0, bb, acc[0][nt]);
                acc[1][nt] = mfma16(a1, bb, acc[1][nt]);
            }
        }
        if (kt < 7) {
            #pragma unroll
            for (int c = 0; c < 4; ++c) {
                *(h8*)&As[alt][sr][sc0 + 8*c] = an[c];
                *(h8*)&Bs[alt][sr][sc0 + 8*c] = bn[c];
            }
            __syncthreads();
            cur = alt;
        }
    }

    #pragma unroll
    for (int nt = 0; nt < 8; ++nt) {
        const int n = y*128 + 16*nt + m;
        const int z = n >> 6, e = n & 63;
        if (z >= 17) continue;
        _Float16* dst; int h;
        if (z < 8)       { dst = kw; h = z; }
        else if (z < 16) { dst = vw; h = z - 8; }
        else             { dst = qw; h = 0; }
        dst += (size_t)h*LL*EE + e;
        #pragma unroll
        for (int mt = 0; mt < 2; ++mt)
            #pragma unroll
            for (int r = 0; r < 4; ++r) {
                int R = r0 + 32*wv + 16*mt + 4*qd + r;
                int b = R >> 10, l = R & 1023;
                dst[((size_t)b*HH*LL + l)*EE] = (_Float16)acc[mt][nt][r];
            }
    }
}

// ---------------- qshuf tile body (depth-3 register pipeline) ------------
__device__ __forceinline__ void qshuf_body(
    int l0, int h,
    const _Float16* __restrict__ xT, const int* __restrict__ perms,
    const _Float16* __restrict__ WT, _Float16* __restrict__ qw,
    _Float16* smem)
{
    auto As = (_Float16(*)[64][72])smem;                 // [2][64][72]
    auto Bs = (_Float16(*)[64][72])(smem + 2*64*72);     // [2][64][72]

    const _Float16* Wb = WT + (size_t)((16 + h)*64)*DD;
    const int* pbase = perms + (size_t)(h-1)*LDX;

    const int t = threadIdx.x;
    const int wv = t >> 6, lane = t & 63;
    const int m = lane & 15, qd = lane >> 4;
    const int lg = t >> 6, kcol = t & 63;
    const int br = t >> 2, bc0 = (t & 3) * 16;

    int pv[8];
    #pragma unroll
    for (int kt = 0; kt < 8; ++kt)
        pv[kt] = pbase[(size_t)(l0 + lg)*DD + kt*64 + kcol];

    h8 g0p[3], g1p[3], b0p[3], b1p[3];
    #pragma unroll
    for (int j = 0; j < 3; ++j) {
        const _Float16* g = xT + (size_t)pv[j] * BB;
        g0p[j] = *(const h8*)g; g1p[j] = *(const h8*)(g + 8);
        const _Float16* s = Wb + (size_t)br*DD + j*64 + bc0;
        b0p[j] = *(const h8*)s; b1p[j] = *(const h8*)(s + 8);
    }

    *(h8*)&Bs[0][br][bc0]     = b0p[0];
    *(h8*)&Bs[0][br][bc0 + 8] = b1p[0];
    #pragma unroll
    for (int i = 0; i < 8; ++i) As[0][lg*16 + i][kcol]     = g0p[0][i];
    #pragma unroll
    for (int i = 0; i < 8; ++i) As[0][lg*16 + 8 + i][kcol] = g1p[0][i];
    __syncthreads();

    f4 acc[4] = {};
    #pragma unroll
    for (int kt = 0; kt < 8; ++kt) {
        const int cur = kt & 1;
        if (kt + 3 < 8) {
            const int st = (kt + 3) % 3;
            const _Float16* g = xT + (size_t)pv[kt+3] * BB;
            g0p[st] = *(const h8*)g; g1p[st] = *(const h8*)(g + 8);
            const _Float16* s = Wb + (size_t)br*DD + (kt+3)*64 + bc0;
            b0p[st] = *(const h8*)s; b1p[st] = *(const h8*)(s + 8);
        }
        #pragma unroll
        for (int ks = 0; ks < 2; ++ks) {
            h8 a = *(const h8*)&As[cur][16*wv + m][32*ks + 8*qd];
            #pragma unroll
            for (int nt = 0; nt < 4; ++nt) {
                h8 bb = *(const h8*)&Bs[cur][16*nt + m][32*ks + 8*qd];
                acc[nt] = mfma16(a, bb, acc[nt]);
            }
        }
        if (kt < 7) {
            const int alt = cur ^ 1;
            const int st = (kt + 1) % 3;
            *(h8*)&Bs[alt][br][bc0]     = b0p[st];
            *(h8*)&Bs[alt][br][bc0 + 8] = b1p[st];
            #pragma unroll
            for (int i = 0; i < 8; ++i) As[alt][lg*16 + i][kcol]     = g0p[st][i];
            #pragma unroll
            for (int i = 0; i < 8; ++i) As[alt][lg*16 + 8 + i][kcol] = g1p[st][i];
            __syncthreads();
        }
    }

    #pragma unroll
    for (int nt = 0; nt < 4; ++nt)
        #pragma unroll
        for (int r = 0; r < 4; ++r) {
            int b = 4*qd + r;
            qw[((size_t)(b*HH + h)*LL + l0 + wv)*EE + 16*nt + m] = (_Float16)acc[nt][r];
        }
}

// ---------------- K1: fused qkv + qshuf, XCD-aware swizzle ---------------
// Memory-throughput-bound at ~3.7 TB/s; FETCH ~258 MB is near floor
// (~190 MB random gather lines + compulsory panel/index reads).
__global__ __launch_bounds__(256) void k_qkv_qshuf(
    const _Float16* __restrict__ x16, const _Float16* __restrict__ xT,
    const int* __restrict__ perms, const _Float16* __restrict__ WT,
    _Float16* __restrict__ qw, _Float16* __restrict__ kw, _Float16* __restrict__ vw)
{
    __shared__ __align__(16) _Float16 smem[4*128*72];   // 73728 B
    const int bx = blockIdx.x;
    const int lx = (bx & 7) * 368 + (bx >> 3);          // XCD-contiguous logical id
    const int g = lx / 23, pos = lx % 23;
    if (pos < 9) {
        const int qid = g*9 + pos;            // [0,1152)
        qkv_body(qid % 9, (qid / 9) * 128, x16, WT, qw, kw, vw, smem);
    } else {
        const int sid = g*14 + (pos - 9);     // [0,1792)
        qshuf_body((sid & 255) * 4, (sid >> 8) + 1, xT, perms, WT, qw, smem);
    }
}

// ---------------- K3: attention v7 — QBLK=256, 8 waves -------------------
__global__ __launch_bounds__(512, 2) void k_attn(
    const _Float16* __restrict__ qw, const _Float16* __restrict__ kw,
    const _Float16* __restrict__ vw, _Float16* __restrict__ oa)
{
    const int bh = blockIdx.x;
    const int l0 = blockIdx.y * 256;
    const int b = bh >> 3, h = bh & 7;
    const _Float16* qb = qw + ((size_t)bh*LL + l0)*EE;
    const _Float16* kb = kw + (size_t)bh*LL*EE;
    const _Float16* vb = vw + (size_t)bh*LL*EE;

    __shared__ __align__(16) _Float16 KsF[2][64*64];
    __shared__ __align__(16) _Float16 VtsF[2][64*64];

    const int t = threadIdx.x;
    const int wv = t >> 6, lane = t & 63;
    const int m = lane & 15, qd = lane >> 4;
    const int m7 = m & 7;
    const int qdp = ((qd & 1) << 1) | (qd >> 1);   // chunk perm from permlane build
    const int krow = t >> 3, c0 = t & 7;           // K staging: 1 h8/thread
    const int vkey = t & 63, vec = t >> 6;         // V staging: vec in 0..7
    const int vhi = vkey >> 3, vlo = vkey & 7;

    h8 qa[2][2];
    #pragma unroll
    for (int mt = 0; mt < 2; ++mt)
        #pragma unroll
        for (int ks = 0; ks < 2; ++ks)
            qa[mt][ks] = *(const h8*)(qb + (size_t)(32*wv + 16*mt + m)*EE + 32*ks + 8*qd);

    f4 oacc[2][4] = {};
    f4 lpacc[2] = {};
    h8 ones;
    #pragma unroll
    for (int i = 0; i < 8; ++i) ones[i] = (_Float16)1.f;

    {   // stage kt=0 into buf 0
        const _Float16* sk = kb + (size_t)krow*EE + 8*c0;
        h8 k0 = *(const h8*)sk;
        const _Float16* sv = vb + (size_t)vkey*EE + 8*vec;
        h8 v0 = *(const h8*)sv;
        *(h8*)&KsF[0][(krow<<6) + 8*(c0 ^ (krow & 7))] = k0;
        #pragma unroll
        for (int i = 0; i < 8; ++i)
            VtsF[0][((8*vec + i)<<6) + 8*(vhi ^ i) + vlo] = v0[i];
    }
    __syncthreads();

    for (int kt = 0; kt < 16; ++kt) {
        const int cur = kt & 1, alt = cur ^ 1;
        h8 kn0, vn0;
        if (kt < 15) {   // prefetch kt+1 into regs
            const _Float16* sk = kb + (size_t)((kt+1)*64 + krow)*EE + 8*c0;
            kn0 = *(const h8*)sk;
            const _Float16* sv = vb + (size_t)((kt+1)*64 + vkey)*EE + 8*vec;
            vn0 = *(const h8*)sv;
        }

        // S^T = K Q^T
        f4 sacc[2][4] = {};
        __builtin_amdgcn_s_setprio(1);
        #pragma unroll
        for (int ks = 0; ks < 2; ++ks)
            #pragma unroll
            for (int nt = 0; nt < 4; ++nt) {
                h8 kf = *(const h8*)&KsF[cur][((16*nt + m)<<6) + 8*((4*ks + qd) ^ m7)];
                sacc[0][nt] = mfma16(kf, qa[0][ks], sacc[0][nt]);
                sacc[1][nt] = mfma16(kf, qa[1][ks], sacc[1][nt]);
            }
        __builtin_amdgcn_s_setprio(0);

        // exp2 + pack pairs
        unsigned E[2][4][2];
        #pragma unroll
        for (int mt = 0; mt < 2; ++mt)
            #pragma unroll
            for (int nt = 0; nt < 4; ++nt) {
                float e0 = __builtin_amdgcn_exp2f(sacc[mt][nt][0]);
                float e1 = __builtin_amdgcn_exp2f(sacc[mt][nt][1]);
                float e2 = __builtin_amdgcn_exp2f(sacc[mt][nt][2]);
                float e3 = __builtin_amdgcn_exp2f(sacc[mt][nt][3]);
                E[mt][nt][0] = __builtin_bit_cast(unsigned, __builtin_amdgcn_cvt_pkrtz(e0, e1));
                E[mt][nt][1] = __builtin_bit_cast(unsigned, __builtin_amdgcn_cvt_pkrtz(e2, e3));
            }

        // permlane16_swap builds PV A-fragments in-register
        h8 pa[2][2];
        #pragma unroll
        for (int mt = 0; mt < 2; ++mt)
            #pragma unroll
            for (int ks = 0; ks < 2; ++ks) {
                auto x = __builtin_amdgcn_permlane16_swap(E[mt][2*ks][0], E[mt][2*ks+1][0], false, false);
                auto y = __builtin_amdgcn_permlane16_swap(E[mt][2*ks][1], E[mt][2*ks+1][1], false, false);
                i4 pw;
                pw[0] = (int)x[0]; pw[1] = (int)y[0]; pw[2] = (int)x[1]; pw[3] = (int)y[1];
                pa[mt][ks] = __builtin_bit_cast(h8, pw);
            }

        // O += P V; lp += P * 1 via MFMA
        __builtin_amdgcn_s_setprio(1);
        #pragma unroll
        for (int ks = 0; ks < 2; ++ks) {
            #pragma unroll
            for (int nt = 0; nt < 4; ++nt) {
                h8 vf = *(const h8*)&VtsF[cur][((16*nt + m)<<6) + 8*((4*ks + qdp) ^ m7)];
                oacc[0][nt] = mfma16(pa[0][ks], vf, oacc[0][nt]);
                oacc[1][nt] = mfma16(pa[1][ks], vf, oacc[1][nt]);
            }
            lpacc[0] = mfma16(pa[0][ks], ones, lpacc[0]);
            lpacc[1] = mfma16(pa[1][ks], ones, lpacc[1]);
        }
        __builtin_amdgcn_s_setprio(0);

        if (kt < 15) {   // commit prefetched tile to buf alt, then barrier
            *(h8*)&KsF[alt][(krow<<6) + 8*(c0 ^ (krow & 7))] = kn0;
            #pragma unroll
            for (int i = 0; i < 8; ++i)
                VtsF[alt][((8*vec + i)<<6) + 8*(vhi ^ i) + vlo] = vn0[i];
            __syncthreads();
        }
    }

    _Float16* ob = oa + ((size_t)(b*LL + l0))*(HH*EE) + h*EE;
    #pragma unroll
    for (int mt = 0; mt < 2; ++mt)
        #pragma unroll
        for (int r = 0; r < 4; ++r) {
            const float inv = __builtin_amdgcn_rcpf(lpacc[mt][r]);
            #pragma unroll
            for (int nt = 0; nt < 4; ++nt) {
                int row = 32*wv + 16*mt + 4*qd + r;
                ob[(size_t)row*(HH*EE) + 16*nt + m] = (_Float16)(oacc[mt][nt][r] * inv);
            }
        }
}

// ---------------- K4: output projection, XCD-aware swizzle ---------------
__global__ __launch_bounds__(256) void k_oproj(
    const _Float16* __restrict__ oa, const _Float16* __restrict__ Wo16,
    const float* __restrict__ bo, float* __restrict__ out)
{
    const int lid = ((int)blockIdx.x & 7) * 64 + ((int)blockIdx.x >> 3);
    const int y  = lid & 3;
    const int r0 = (lid >> 2) * 128;

    __shared__ __align__(16) _Float16 As[2][128][72];
    __shared__ __align__(16) _Float16 Bs[2][128][72];

    const int t = threadIdx.x;
    const int wv = t >> 6, lane = t & 63;
    const int m = lane & 15, qd = lane >> 4;
    const int sr = t >> 1, sc0 = (t & 1) * 32;

    const _Float16* ax = oa   + (size_t)(r0 + sr)*DD + sc0;
    const _Float16* bx = Wo16 + (size_t)(y*128 + sr)*DD + sc0;

    #pragma unroll
    for (int c = 0; c < 4; ++c) {
        *(h8*)&As[0][sr][sc0 + 8*c] = *(const h8*)(ax + 8*c);
        *(h8*)&Bs[0][sr][sc0 + 8*c] = *(const h8*)(bx + 8*c);
    }
    __syncthreads();

    f4 acc[2][8] = {};
    int cur = 0;
    for (int kt = 0; kt < 8; ++kt) {
        const int alt = cur ^ 1;
        h8 an[4], bn[4];
        if (kt < 7) {
            const _Float16* a2 = ax + (kt+1)*64;
            const _Float16* b2 = bx + (kt+1)*64;
            #pragma unroll
            for (int c = 0; c < 4; ++c) {
                an[c] = *(const h8*)(a2 + 8*c);
                bn[c] = *(const h8*)(b2 + 8*c);
            }
        }
        #pragma unroll
        for (int ks = 0; ks < 2; ++ks) {
            h8 a0 = *(const h8*)&As[cur][32*wv +  0 + m][32*ks + 8*qd];
            h8 a1 = *(const h8*)&As[cur][32*wv + 16 + m][32*ks + 8*qd];
            #pragma unroll
            for (int nt = 0; nt < 8; ++nt) {
                h8 bb = *(const h8*)&Bs[cur][16*nt + m][32*ks + 8*qd];
                acc[0][nt] = mfma16(a0, bb, acc[0][nt]);
                acc[1][nt] = mfma16(a1, bb, acc[1][nt]);
            }
        }
        if (kt < 7) {
            #pragma unroll
            for (int c = 0; c < 4; ++c) {
                *(h8*)&As[alt][sr][sc0 + 8*c] = an[c];
                *(h8*)&Bs[alt][sr][sc0 + 8*c] = bn[c];
            }
            __syncthreads();
            cur = alt;
        }
    }

    #pragma unroll
    for (int nt = 0; nt < 8; ++nt) {
        const int col = y*128 + 16*nt + m;
        const float bias = bo[col];
        #pragma unroll
        for (int mt = 0; mt < 2; ++mt)
            #pragma unroll
            for (int r = 0; r < 4; ++r) {
                int row = 32*wv + 16*mt + 4*qd + r;
                out[(size_t)(r0 + row)*DD + col] = acc[mt][nt][r] + bias;
            }
    }
}

extern "C" void kernel_launch(void* const* d_in, const int* in_sizes, int n_in,
                              void* d_out, int out_size, void* d_ws, size_t ws_size,
                              hipStream_t stream)
{
    const float* x  = (const float*)d_in[0];
    const int*   pm = (const int*)d_in[1];
    const float* Wq = (const float*)d_in[2];
    const float* Wk = (const float*)d_in[3];
    const float* Wv = (const float*)d_in[4];
    const float* Wo = (const float*)d_in[5];
    const float* bo = (const float*)d_in[6];
    float* out = (float*)d_out;

    const size_t QS = (size_t)BB * HH * LL * EE;
    _Float16* q    = (_Float16*)d_ws;
    _Float16* k    = q + QS;
    _Float16* v    = k + QS;
    _Float16* oaw  = v + QS;
    _Float16* xT   = oaw;              // alias: dead before k_attn writes oaw
    _Float16* WT   = oaw + QS;
    _Float16* Wo16 = WT + (size_t)24*64*DD;
    _Float16* x16  = (_Float16*)d_out; // scratch: dead before k_oproj writes out

    k_prep_all <<<dim3(2048 + 192 + 256), 256, 0, stream>>>(
        x, Wq, Wk, Wv, Wo, xT, x16, WT, Wo16);
    k_qkv_qshuf<<<dim3(2944),          256, 0, stream>>>(x16, xT, pm, WT, q, k, v);
    k_attn     <<<dim3(BB*HH, LL/256), 512, 0, stream>>>(q, k, v, oaw);
    k_oproj    <<<dim3(512),           256, 0, stream>>>(oaw, Wo16, bo, out);
}

// Round 7
// 245.497 us; speedup vs baseline: 1.0845x; 1.0092x over previous
//
#include <hip/hip_runtime.h>

#define LL 1024
#define DD 512
#define HH 8
#define EE 64
#define LDX (LL*DD)
#define BB 16

typedef _Float16 h8 __attribute__((ext_vector_type(8)));
typedef _Float16 h4 __attribute__((ext_vector_type(4)));
typedef float f4 __attribute__((ext_vector_type(4)));
typedef int i4 __attribute__((ext_vector_type(4)));

__device__ __forceinline__ f4 mfma16(h8 a, h8 b, f4 c) {
    return __builtin_amdgcn_mfma_f32_16x16x32_f16(a, b, c, 0, 0, 0);
}

// ---------------- P: prep, x read ONCE for both xT and x16 ---------------
__global__ __launch_bounds__(256) void k_prep_all(
    const float* __restrict__ x,  const float* __restrict__ Wq,
    const float* __restrict__ Wk, const float* __restrict__ Wv,
    const float* __restrict__ Wo,
    _Float16* __restrict__ xT, _Float16* __restrict__ x16,
    _Float16* __restrict__ WT, _Float16* __restrict__ Wo16)
{
    const int bx = blockIdx.x;
    const int t = threadIdx.x;
    if (bx < 2048) {
        const int s = bx * 256 + t;
        h8 lo, hi;
        #pragma unroll
        for (int b = 0; b < 8; ++b)  lo[b] = (_Float16)x[(size_t)b*LDX + s];
        #pragma unroll
        for (int b = 0; b < 8; ++b)  hi[b] = (_Float16)x[(size_t)(b+8)*LDX + s];
        _Float16* d = xT + (size_t)s * BB;
        *(h8*)d = lo; *(h8*)(d + 8) = hi;
        #pragma unroll
        for (int b = 0; b < 8; ++b)  x16[(size_t)b*LDX + s]     = lo[b];
        #pragma unroll
        for (int b = 0; b < 8; ++b)  x16[(size_t)(b+8)*LDX + s] = hi[b];
    } else if (bx < 2048 + 192) {
        const int id = bx - 2048;
        const int d0 = (id & 7) * 64;
        const int zz = id >> 3;
        const float* src; float sc = 1.f;
        if (zz < 8)       src = Wk + (size_t)zz*DD*EE;
        else if (zz < 16) src = Wv + (size_t)(zz-8)*DD*EE;
        else            { src = Wq + (size_t)(zz-16)*DD*EE; sc = 0.18033688011112042f; }
        const int e = t & 63, dq = t >> 6;
        #pragma unroll
        for (int i = 0; i < 16; ++i) {
            int d = d0 + dq*16 + i;
            WT[(size_t)(zz*64 + e)*DD + d] = (_Float16)(src[(size_t)d*EE + e] * sc);
        }
    } else {
        const int i = (bx - (2048 + 192)) * 256 + t;
        f4 v = ((const f4*)Wo)[i];
        #pragma unroll
        for (int j = 0; j < 4; ++j) Wo16[4*i + j] = (_Float16)v[j];
    }
}

// ---------------- qkv tile body (M128xN128, pipelined, f16 A) ------------
__device__ __forceinline__ void qkv_body(
    int y, int r0,
    const _Float16* __restrict__ x16, const _Float16* __restrict__ WT,
    _Float16* __restrict__ qw, _Float16* __restrict__ kw, _Float16* __restrict__ vw,
    _Float16* smem)
{
    auto As = (_Float16(*)[128][72])smem;                 // [2][128][72]
    auto Bs = (_Float16(*)[128][72])(smem + 2*128*72);    // [2][128][72]

    const int t = threadIdx.x;
    const int wv = t >> 6, lane = t & 63;
    const int m = lane & 15, qd = lane >> 4;
    const int sr = t >> 1, sc0 = (t & 1) * 32;

    const _Float16* ax = x16 + (size_t)(r0 + sr)*DD + sc0;
    const _Float16* bx = WT  + (size_t)(y*128 + sr)*DD + sc0;

    #pragma unroll
    for (int c = 0; c < 4; ++c) {
        *(h8*)&As[0][sr][sc0 + 8*c] = *(const h8*)(ax + 8*c);
        *(h8*)&Bs[0][sr][sc0 + 8*c] = *(const h8*)(bx + 8*c);
    }
    __syncthreads();

    f4 acc[2][8] = {};
    int cur = 0;
    for (int kt = 0; kt < 8; ++kt) {
        const int alt = cur ^ 1;
        h8 an[4], bn[4];
        if (kt < 7) {
            const _Float16* a2 = ax + (kt+1)*64;
            const _Float16* b2 = bx + (kt+1)*64;
            #pragma unroll
            for (int c = 0; c < 4; ++c) {
                an[c] = *(const h8*)(a2 + 8*c);
                bn[c] = *(const h8*)(b2 + 8*c);
            }
        }
        #pragma unroll
        for (int ks = 0; ks < 2; ++ks) {
            h8 a0 = *(const h8*)&As[cur][32*wv +  0 + m][32*ks + 8*qd];
            h8 a1 = *(const h8*)&As[cur][32*wv + 16 + m][32*ks + 8*qd];
            #pragma unroll
            for (int nt = 0; nt < 8; ++nt) {
                h8 bb = *(const h8*)&Bs[cur][16*nt + m][32*ks + 8*qd];
                acc[0][nt] = mfma16(a0, bb, acc[0][nt]);
                acc[1][nt] = mfma16(a1, bb, acc[1][nt]);
            }
        }
        if (kt < 7) {
            #pragma unroll
            for (int c = 0; c < 4; ++c) {
                *(h8*)&As[alt][sr][sc0 + 8*c] = an[c];
                *(h8*)&Bs[alt][sr][sc0 + 8*c] = bn[c];
            }
            __syncthreads();
            cur = alt;
        }
    }

    #pragma unroll
    for (int nt = 0; nt < 8; ++nt) {
        const int n = y*128 + 16*nt + m;
        const int z = n >> 6, e = n & 63;
        if (z >= 17) continue;
        _Float16* dst; int h;
        if (z < 8)       { dst = kw; h = z; }
        else if (z < 16) { dst = vw; h = z - 8; }
        else             { dst = qw; h = 0; }
        dst += (size_t)h*LL*EE + e;
        #pragma unroll
        for (int mt = 0; mt < 2; ++mt)
            #pragma unroll
            for (int r = 0; r < 4; ++r) {
                int R = r0 + 32*wv + 16*mt + 4*qd + r;
                int b = R >> 10, l = R & 1023;
                dst[((size_t)b*HH*LL + l)*EE] = (_Float16)acc[mt][nt][r];
            }
    }
}

// ---------------- qshuf tile body (depth-3 register pipeline) ------------
__device__ __forceinline__ void qshuf_body(
    int l0, int h,
    const _Float16* __restrict__ xT, const int* __restrict__ perms,
    const _Float16* __restrict__ WT, _Float16* __restrict__ qw,
    _Float16* smem)
{
    auto As = (_Float16(*)[64][72])smem;                 // [2][64][72]
    auto Bs = (_Float16(*)[64][72])(smem + 2*64*72);     // [2][64][72]

    const _Float16* Wb = WT + (size_t)((16 + h)*64)*DD;
    const int* pbase = perms + (size_t)(h-1)*LDX;

    const int t = threadIdx.x;
    const int wv = t >> 6, lane = t & 63;
    const int m = lane & 15, qd = lane >> 4;
    const int lg = t >> 6, kcol = t & 63;
    const int br = t >> 2, bc0 = (t & 3) * 16;

    int pv[8];
    #pragma unroll
    for (int kt = 0; kt < 8; ++kt)
        pv[kt] = pbase[(size_t)(l0 + lg)*DD + kt*64 + kcol];

    h8 g0p[3], g1p[3], b0p[3], b1p[3];
    #pragma unroll
    for (int j = 0; j < 3; ++j) {
        const _Float16* g = xT + (size_t)pv[j] * BB;
        g0p[j] = *(const h8*)g; g1p[j] = *(const h8*)(g + 8);
        const _Float16* s = Wb + (size_t)br*DD + j*64 + bc0;
        b0p[j] = *(const h8*)s; b1p[j] = *(const h8*)(s + 8);
    }

    *(h8*)&Bs[0][br][bc0]     = b0p[0];
    *(h8*)&Bs[0][br][bc0 + 8] = b1p[0];
    #pragma unroll
    for (int i = 0; i < 8; ++i) As[0][lg*16 + i][kcol]     = g0p[0][i];
    #pragma unroll
    for (int i = 0; i < 8; ++i) As[0][lg*16 + 8 + i][kcol] = g1p[0][i];
    __syncthreads();

    f4 acc[4] = {};
    #pragma unroll
    for (int kt = 0; kt < 8; ++kt) {
        const int cur = kt & 1;
        if (kt + 3 < 8) {
            const int st = (kt + 3) % 3;
            const _Float16* g = xT + (size_t)pv[kt+3] * BB;
            g0p[st] = *(const h8*)g; g1p[st] = *(const h8*)(g + 8);
            const _Float16* s = Wb + (size_t)br*DD + (kt+3)*64 + bc0;
            b0p[st] = *(const h8*)s; b1p[st] = *(const h8*)(s + 8);
        }
        #pragma unroll
        for (int ks = 0; ks < 2; ++ks) {
            h8 a = *(const h8*)&As[cur][16*wv + m][32*ks + 8*qd];
            #pragma unroll
            for (int nt = 0; nt < 4; ++nt) {
                h8 bb = *(const h8*)&Bs[cur][16*nt + m][32*ks + 8*qd];
                acc[nt] = mfma16(a, bb, acc[nt]);
            }
        }
        if (kt < 7) {
            const int alt = cur ^ 1;
            const int st = (kt + 1) % 3;
            *(h8*)&Bs[alt][br][bc0]     = b0p[st];
            *(h8*)&Bs[alt][br][bc0 + 8] = b1p[st];
            #pragma unroll
            for (int i = 0; i < 8; ++i) As[alt][lg*16 + i][kcol]     = g0p[st][i];
            #pragma unroll
            for (int i = 0; i < 8; ++i) As[alt][lg*16 + 8 + i][kcol] = g1p[st][i];
            __syncthreads();
        }
    }

    #pragma unroll
    for (int nt = 0; nt < 4; ++nt)
        #pragma unroll
        for (int r = 0; r < 4; ++r) {
            int b = 4*qd + r;
            qw[((size_t)(b*HH + h)*LL + l0 + wv)*EE + 16*nt + m] = (_Float16)acc[nt][r];
        }
}

// ---------------- K1: fused qkv + qshuf, XCD-aware swizzle ---------------
__global__ __launch_bounds__(256) void k_qkv_qshuf(
    const _Float16* __restrict__ x16, const _Float16* __restrict__ xT,
    const int* __restrict__ perms, const _Float16* __restrict__ WT,
    _Float16* __restrict__ qw, _Float16* __restrict__ kw, _Float16* __restrict__ vw)
{
    __shared__ __align__(16) _Float16 smem[4*128*72];   // 73728 B
    const int bx = blockIdx.x;
    const int lx = (bx & 7) * 368 + (bx >> 3);          // XCD-contiguous logical id
    const int g = lx / 23, pos = lx % 23;
    if (pos < 9) {
        const int qid = g*9 + pos;            // [0,1152)
        qkv_body(qid % 9, (qid / 9) * 128, x16, WT, qw, kw, vw, smem);
    } else {
        const int sid = g*14 + (pos - 9);     // [0,1792)
        qshuf_body((sid & 255) * 4, (sid >> 8) + 1, xT, perms, WT, qw, smem);
    }
}

// ---------------- K3: attention v8 — 4 buffers, 1 barrier / 2 tiles ------
// v7 paid 16 barriers (one per K-tile); with 4 K/V buffers (64 KB LDS,
// still 2 blocks/CU) tile 2j+2 overwrites the buffer freed before the last
// barrier, so one barrier serves two tiles: 8 barriers total, and two
// tiles' global loads in flight per period.
__global__ __launch_bounds__(512, 2) void k_attn(
    const _Float16* __restrict__ qw, const _Float16* __restrict__ kw,
    const _Float16* __restrict__ vw, _Float16* __restrict__ oa)
{
    const int bh = blockIdx.x;
    const int l0 = blockIdx.y * 256;
    const int b = bh >> 3, h = bh & 7;
    const _Float16* qb = qw + ((size_t)bh*LL + l0)*EE;
    const _Float16* kb = kw + (size_t)bh*LL*EE;
    const _Float16* vb = vw + (size_t)bh*LL*EE;

    __shared__ __align__(16) _Float16 KsF[4][64*64];
    __shared__ __align__(16) _Float16 VtsF[4][64*64];

    const int t = threadIdx.x;
    const int wv = t >> 6, lane = t & 63;
    const int m = lane & 15, qd = lane >> 4;
    const int m7 = m & 7;
    const int qdp = ((qd & 1) << 1) | (qd >> 1);   // chunk perm from permlane build
    const int krow = t >> 3, c0 = t & 7;           // K staging: 1 h8/thread
    const int vkey = t & 63, vec = t >> 6;         // V staging: vec in 0..7
    const int vhi = vkey >> 3, vlo = vkey & 7;

    h8 qa[2][2];
    #pragma unroll
    for (int mt = 0; mt < 2; ++mt)
        #pragma unroll
        for (int ks = 0; ks < 2; ++ks)
            qa[mt][ks] = *(const h8*)(qb + (size_t)(32*wv + 16*mt + m)*EE + 32*ks + 8*qd);

    f4 oacc[2][4] = {};
    f4 lpacc[2] = {};
    h8 ones;
    #pragma unroll
    for (int i = 0; i < 8; ++i) ones[i] = (_Float16)1.f;

    auto loadK = [&](int kt) -> h8 {
        return *(const h8*)(kb + (size_t)(kt*64 + krow)*EE + 8*c0);
    };
    auto loadV = [&](int kt) -> h8 {
        return *(const h8*)(vb + (size_t)(kt*64 + vkey)*EE + 8*vec);
    };
    auto stageK = [&](int buf, h8 kr) {
        *(h8*)&KsF[buf][(krow<<6) + 8*(c0 ^ (krow & 7))] = kr;
    };
    auto stageV = [&](int buf, h8 vr) {
        #pragma unroll
        for (int i = 0; i < 8; ++i)
            VtsF[buf][((8*vec + i)<<6) + 8*(vhi ^ i) + vlo] = vr[i];
    };
    auto compute = [&](int buf) {
        f4 sacc[2][4] = {};
        __builtin_amdgcn_s_setprio(1);
        #pragma unroll
        for (int ks = 0; ks < 2; ++ks)
            #pragma unroll
            for (int nt = 0; nt < 4; ++nt) {
                h8 kf = *(const h8*)&KsF[buf][((16*nt + m)<<6) + 8*((4*ks + qd) ^ m7)];
                sacc[0][nt] = mfma16(kf, qa[0][ks], sacc[0][nt]);
                sacc[1][nt] = mfma16(kf, qa[1][ks], sacc[1][nt]);
            }
        __builtin_amdgcn_s_setprio(0);

        unsigned E[2][4][2];
        #pragma unroll
        for (int mt = 0; mt < 2; ++mt)
            #pragma unroll
            for (int nt = 0; nt < 4; ++nt) {
                float e0 = __builtin_amdgcn_exp2f(sacc[mt][nt][0]);
                float e1 = __builtin_amdgcn_exp2f(sacc[mt][nt][1]);
                float e2 = __builtin_amdgcn_exp2f(sacc[mt][nt][2]);
                float e3 = __builtin_amdgcn_exp2f(sacc[mt][nt][3]);
                E[mt][nt][0] = __builtin_bit_cast(unsigned, __builtin_amdgcn_cvt_pkrtz(e0, e1));
                E[mt][nt][1] = __builtin_bit_cast(unsigned, __builtin_amdgcn_cvt_pkrtz(e2, e3));
            }

        h8 pa[2][2];
        #pragma unroll
        for (int mt = 0; mt < 2; ++mt)
            #pragma unroll
            for (int ks = 0; ks < 2; ++ks) {
                auto xx = __builtin_amdgcn_permlane16_swap(E[mt][2*ks][0], E[mt][2*ks+1][0], false, false);
                auto yy = __builtin_amdgcn_permlane16_swap(E[mt][2*ks][1], E[mt][2*ks+1][1], false, false);
                i4 pw;
                pw[0] = (int)xx[0]; pw[1] = (int)yy[0]; pw[2] = (int)xx[1]; pw[3] = (int)yy[1];
                pa[mt][ks] = __builtin_bit_cast(h8, pw);
            }

        __builtin_amdgcn_s_setprio(1);
        #pragma unroll
        for (int ks = 0; ks < 2; ++ks) {
            #pragma unroll
            for (int nt = 0; nt < 4; ++nt) {
                h8 vf = *(const h8*)&VtsF[buf][((16*nt + m)<<6) + 8*((4*ks + qdp) ^ m7)];
                oacc[0][nt] = mfma16(pa[0][ks], vf, oacc[0][nt]);
                oacc[1][nt] = mfma16(pa[1][ks], vf, oacc[1][nt]);
            }
            lpacc[0] = mfma16(pa[0][ks], ones, lpacc[0]);
            lpacc[1] = mfma16(pa[1][ks], ones, lpacc[1]);
        }
        __builtin_amdgcn_s_setprio(0);
    };

    // prologue: tiles 0,1 into buffers 0,1
    {
        h8 k0 = loadK(0), v0 = loadV(0), k1 = loadK(1), v1 = loadV(1);
        stageK(0, k0); stageV(0, v0);
        stageK(1, k1); stageV(1, v1);
    }
    __syncthreads();

    #pragma unroll
    for (int j = 0; j < 8; ++j) {
        h8 ka, va, kc, vc;
        if (j < 7) {
            ka = loadK(2*j + 2); va = loadV(2*j + 2);
            kc = loadK(2*j + 3); vc = loadV(2*j + 3);
        }
        compute((2*j) & 3);
        if (j < 7) { stageK((2*j + 2) & 3, ka); stageV((2*j + 2) & 3, va); }
        compute((2*j + 1) & 3);
        if (j < 7) {
            stageK((2*j + 3) & 3, kc); stageV((2*j + 3) & 3, vc);
            __syncthreads();
        }
    }

    _Float16* ob = oa + ((size_t)(b*LL + l0))*(HH*EE) + h*EE;
    #pragma unroll
    for (int mt = 0; mt < 2; ++mt)
        #pragma unroll
        for (int r = 0; r < 4; ++r) {
            const float inv = __builtin_amdgcn_rcpf(lpacc[mt][r]);
            #pragma unroll
            for (int nt = 0; nt < 4; ++nt) {
                int row = 32*wv + 16*mt + 4*qd + r;
                ob[(size_t)row*(HH*EE) + 16*nt + m] = (_Float16)(oacc[mt][nt][r] * inv);
            }
        }
}

// ---------------- K4: output projection, XCD-aware swizzle ---------------
__global__ __launch_bounds__(256) void k_oproj(
    const _Float16* __restrict__ oa, const _Float16* __restrict__ Wo16,
    const float* __restrict__ bo, float* __restrict__ out)
{
    const int lid = ((int)blockIdx.x & 7) * 64 + ((int)blockIdx.x >> 3);
    const int y  = lid & 3;
    const int r0 = (lid >> 2) * 128;

    __shared__ __align__(16) _Float16 As[2][128][72];
    __shared__ __align__(16) _Float16 Bs[2][128][72];

    const int t = threadIdx.x;
    const int wv = t >> 6, lane = t & 63;
    const int m = lane & 15, qd = lane >> 4;
    const int sr = t >> 1, sc0 = (t & 1) * 32;

    const _Float16* ax = oa   + (size_t)(r0 + sr)*DD + sc0;
    const _Float16* bx = Wo16 + (size_t)(y*128 + sr)*DD + sc0;

    #pragma unroll
    for (int c = 0; c < 4; ++c) {
        *(h8*)&As[0][sr][sc0 + 8*c] = *(const h8*)(ax + 8*c);
        *(h8*)&Bs[0][sr][sc0 + 8*c] = *(const h8*)(bx + 8*c);
    }
    __syncthreads();

    f4 acc[2][8] = {};
    int cur = 0;
    for (int kt = 0; kt < 8; ++kt) {
        const int alt = cur ^ 1;
        h8 an[4], bn[4];
        if (kt < 7) {
            const _Float16* a2 = ax + (kt+1)*64;
            const _Float16* b2 = bx + (kt+1)*64;
            #pragma unroll
            for (int c = 0; c < 4; ++c) {
                an[c] = *(const h8*)(a2 + 8*c);
                bn[c] = *(const h8*)(b2 + 8*c);
            }
        }
        #pragma unroll
        for (int ks = 0; ks < 2; ++ks) {
            h8 a0 = *(const h8*)&As[cur][32*wv +  0 + m][32*ks + 8*qd];
            h8 a1 = *(const h8*)&As[cur][32*wv + 16 + m][32*ks + 8*qd];
            #pragma unroll
            for (int nt = 0; nt < 8; ++nt) {
                h8 bb = *(const h8*)&Bs[cur][16*nt + m][32*ks + 8*qd];
                acc[0][nt] = mfma16(a0, bb, acc[0][nt]);
                acc[1][nt] = mfma16(a1, bb, acc[1][nt]);
            }
        }
        if (kt < 7) {
            #pragma unroll
            for (int c = 0; c < 4; ++c) {
                *(h8*)&As[alt][sr][sc0 + 8*c] = an[c];
                *(h8*)&Bs[alt][sr][sc0 + 8*c] = bn[c];
            }
            __syncthreads();
            cur = alt;
        }
    }

    #pragma unroll
    for (int nt = 0; nt < 8; ++nt) {
        const int col = y*128 + 16*nt + m;
        const float bias = bo[col];
        #pragma unroll
        for (int mt = 0; mt < 2; ++mt)
            #pragma unroll
            for (int r = 0; r < 4; ++r) {
                int row = 32*wv + 16*mt + 4*qd + r;
                out[(size_t)(r0 + row)*DD + col] = acc[mt][nt][r] + bias;
            }
    }
}

extern "C" void kernel_launch(void* const* d_in, const int* in_sizes, int n_in,
                              void* d_out, int out_size, void* d_ws, size_t ws_size,
                              hipStream_t stream)
{
    const float* x  = (const float*)d_in[0];
    const int*   pm = (const int*)d_in[1];
    const float* Wq = (const float*)d_in[2];
    const float* Wk = (const float*)d_in[3];
    const float* Wv = (const float*)d_in[4];
    const float* Wo = (const float*)d_in[5];
    const float* bo = (const float*)d_in[6];
    float* out = (float*)d_out;

    const size_t QS = (size_t)BB * HH * LL * EE;   // 8388608 elements (16.78 MB)
    // d_out (33.55 MB) hosts x16 and q, both dead before k_oproj writes out.
    _Float16* x16  = (_Float16*)d_out;
    _Float16* q    = (_Float16*)d_out + QS;
    _Float16* k    = (_Float16*)d_ws;
    _Float16* v    = k + QS;
    _Float16* oaw  = v + QS;
    _Float16* xT   = oaw;              // alias: dead before k_attn writes oaw
    _Float16* WT   = oaw + QS;
    _Float16* Wo16 = WT + (size_t)24*64*DD;

    k_prep_all <<<dim3(2048 + 192 + 256), 256, 0, stream>>>(
        x, Wq, Wk, Wv, Wo, xT, x16, WT, Wo16);
    k_qkv_qshuf<<<dim3(2944),          256, 0, stream>>>(x16, xT, pm, WT, q, k, v);
    k_attn     <<<dim3(BB*HH, LL/256), 512, 0, stream>>>(q, k, v, oaw);
    k_oproj    <<<dim3(512),           256, 0, stream>>>(oaw, Wo16, bo, out);
}

// Round 8
// 240.179 us; speedup vs baseline: 1.1085x; 1.0221x over previous
//
#include <hip/hip_runtime.h>

#define LL 1024
#define DD 512
#define HH 8
#define EE 64
#define LDX (LL*DD)
#define BB 16

typedef _Float16 h8 __attribute__((ext_vector_type(8)));
typedef _Float16 h4 __attribute__((ext_vector_type(4)));
typedef float f4 __attribute__((ext_vector_type(4)));
typedef int i4 __attribute__((ext_vector_type(4)));

__device__ __forceinline__ f4 mfma16(h8 a, h8 b, f4 c) {
    return __builtin_amdgcn_mfma_f32_16x16x32_f16(a, b, c, 0, 0, 0);
}

// ---------------- P: prep, x read ONCE for both xT and x16 ---------------
__global__ __launch_bounds__(256) void k_prep_all(
    const float* __restrict__ x,  const float* __restrict__ Wq,
    const float* __restrict__ Wk, const float* __restrict__ Wv,
    const float* __restrict__ Wo,
    _Float16* __restrict__ xT, _Float16* __restrict__ x16,
    _Float16* __restrict__ WT, _Float16* __restrict__ Wo16)
{
    const int bx = blockIdx.x;
    const int t = threadIdx.x;
    if (bx < 2048) {
        const int s = bx * 256 + t;
        h8 lo, hi;
        #pragma unroll
        for (int b = 0; b < 8; ++b)  lo[b] = (_Float16)x[(size_t)b*LDX + s];
        #pragma unroll
        for (int b = 0; b < 8; ++b)  hi[b] = (_Float16)x[(size_t)(b+8)*LDX + s];
        _Float16* d = xT + (size_t)s * BB;
        *(h8*)d = lo; *(h8*)(d + 8) = hi;
        #pragma unroll
        for (int b = 0; b < 8; ++b)  x16[(size_t)b*LDX + s]     = lo[b];
        #pragma unroll
        for (int b = 0; b < 8; ++b)  x16[(size_t)(b+8)*LDX + s] = hi[b];
    } else if (bx < 2048 + 192) {
        const int id = bx - 2048;
        const int d0 = (id & 7) * 64;
        const int zz = id >> 3;
        const float* src; float sc = 1.f;
        if (zz < 8)       src = Wk + (size_t)zz*DD*EE;
        else if (zz < 16) src = Wv + (size_t)(zz-8)*DD*EE;
        else            { src = Wq + (size_t)(zz-16)*DD*EE; sc = 0.18033688011112042f; }
        const int e = t & 63, dq = t >> 6;
        #pragma unroll
        for (int i = 0; i < 16; ++i) {
            int d = d0 + dq*16 + i;
            WT[(size_t)(zz*64 + e)*DD + d] = (_Float16)(src[(size_t)d*EE + e] * sc);
        }
    } else {
        const int i = (bx - (2048 + 192)) * 256 + t;
        f4 v = ((const f4*)Wo)[i];
        #pragma unroll
        for (int j = 0; j < 4; ++j) Wo16[4*i + j] = (_Float16)v[j];
    }
}

// ---------------- qkv tile body (M128xN128, pipelined, f16 A) ------------
__device__ __forceinline__ void qkv_body(
    int y, int r0,
    const _Float16* __restrict__ x16, const _Float16* __restrict__ WT,
    _Float16* __restrict__ qw, _Float16* __restrict__ kw, _Float16* __restrict__ vw,
    _Float16* smem)
{
    auto As = (_Float16(*)[128][72])smem;                 // [2][128][72]
    auto Bs = (_Float16(*)[128][72])(smem + 2*128*72);    // [2][128][72]

    const int t = threadIdx.x;
    const int wv = t >> 6, lane = t & 63;
    const int m = lane & 15, qd = lane >> 4;
    const int sr = t >> 1, sc0 = (t & 1) * 32;

    const _Float16* ax = x16 + (size_t)(r0 + sr)*DD + sc0;
    const _Float16* bx = WT  + (size_t)(y*128 + sr)*DD + sc0;

    #pragma unroll
    for (int c = 0; c < 4; ++c) {
        *(h8*)&As[0][sr][sc0 + 8*c] = *(const h8*)(ax + 8*c);
        *(h8*)&Bs[0][sr][sc0 + 8*c] = *(const h8*)(bx + 8*c);
    }
    __syncthreads();

    f4 acc[2][8] = {};
    int cur = 0;
    for (int kt = 0; kt < 8; ++kt) {
        const int alt = cur ^ 1;
        h8 an[4], bn[4];
        if (kt < 7) {
            const _Float16* a2 = ax + (kt+1)*64;
            const _Float16* b2 = bx + (kt+1)*64;
            #pragma unroll
            for (int c = 0; c < 4; ++c) {
                an[c] = *(const h8*)(a2 + 8*c);
                bn[c] = *(const h8*)(b2 + 8*c);
            }
        }
        #pragma unroll
        for (int ks = 0; ks < 2; ++ks) {
            h8 a0 = *(const h8*)&As[cur][32*wv +  0 + m][32*ks + 8*qd];
            h8 a1 = *(const h8*)&As[cur][32*wv + 16 + m][32*ks + 8*qd];
            #pragma unroll
            for (int nt = 0; nt < 8; ++nt) {
                h8 bb = *(const h8*)&Bs[cur][16*nt + m][32*ks + 8*qd];
                acc[0][nt] = mfma16(a0, bb, acc[0][nt]);
                acc[1][nt] = mfma16(a1, bb, acc[1][nt]);
            }
        }
        if (kt < 7) {
            #pragma unroll
            for (int c = 0; c < 4; ++c) {
                *(h8*)&As[alt][sr][sc0 + 8*c] = an[c];
                *(h8*)&Bs[alt][sr][sc0 + 8*c] = bn[c];
            }
            __syncthreads();
            cur = alt;
        }
    }

    #pragma unroll
    for (int nt = 0; nt < 8; ++nt) {
        const int n = y*128 + 16*nt + m;
        const int z = n >> 6, e = n & 63;
        if (z >= 17) continue;
        _Float16* dst; int h;
        if (z < 8)       { dst = kw; h = z; }
        else if (z < 16) { dst = vw; h = z - 8; }
        else             { dst = qw; h = 0; }
        dst += (size_t)h*LL*EE + e;
        #pragma unroll
        for (int mt = 0; mt < 2; ++mt)
            #pragma unroll
            for (int r = 0; r < 4; ++r) {
                int R = r0 + 32*wv + 16*mt + 4*qd + r;
                int b = R >> 10, l = R & 1023;
                dst[((size_t)b*HH*LL + l)*EE] = (_Float16)acc[mt][nt][r];
            }
    }
}

// ---------------- qshuf tile body (depth-3 register pipeline) ------------
__device__ __forceinline__ void qshuf_body(
    int l0, int h,
    const _Float16* __restrict__ xT, const int* __restrict__ perms,
    const _Float16* __restrict__ WT, _Float16* __restrict__ qw,
    _Float16* smem)
{
    auto As = (_Float16(*)[64][72])smem;                 // [2][64][72]
    auto Bs = (_Float16(*)[64][72])(smem + 2*64*72);     // [2][64][72]

    const _Float16* Wb = WT + (size_t)((16 + h)*64)*DD;
    const int* pbase = perms + (size_t)(h-1)*LDX;

    const int t = threadIdx.x;
    const int wv = t >> 6, lane = t & 63;
    const int m = lane & 15, qd = lane >> 4;
    const int lg = t >> 6, kcol = t & 63;
    const int br = t >> 2, bc0 = (t & 3) * 16;

    int pv[8];
    #pragma unroll
    for (int kt = 0; kt < 8; ++kt)
        pv[kt] = pbase[(size_t)(l0 + lg)*DD + kt*64 + kcol];

    h8 g0p[3], g1p[3], b0p[3], b1p[3];
    #pragma unroll
    for (int j = 0; j < 3; ++j) {
        const _Float16* g = xT + (size_t)pv[j] * BB;
        g0p[j] = *(const h8*)g; g1p[j] = *(const h8*)(g + 8);
        const _Float16* s = Wb + (size_t)br*DD + j*64 + bc0;
        b0p[j] = *(const h8*)s; b1p[j] = *(const h8*)(s + 8);
    }

    *(h8*)&Bs[0][br][bc0]     = b0p[0];
    *(h8*)&Bs[0][br][bc0 + 8] = b1p[0];
    #pragma unroll
    for (int i = 0; i < 8; ++i) As[0][lg*16 + i][kcol]     = g0p[0][i];
    #pragma unroll
    for (int i = 0; i < 8; ++i) As[0][lg*16 + 8 + i][kcol] = g1p[0][i];
    __syncthreads();

    f4 acc[4] = {};
    #pragma unroll
    for (int kt = 0; kt < 8; ++kt) {
        const int cur = kt & 1;
        if (kt + 3 < 8) {
            const int st = (kt + 3) % 3;
            const _Float16* g = xT + (size_t)pv[kt+3] * BB;
            g0p[st] = *(const h8*)g; g1p[st] = *(const h8*)(g + 8);
            const _Float16* s = Wb + (size_t)br*DD + (kt+3)*64 + bc0;
            b0p[st] = *(const h8*)s; b1p[st] = *(const h8*)(s + 8);
        }
        #pragma unroll
        for (int ks = 0; ks < 2; ++ks) {
            h8 a = *(const h8*)&As[cur][16*wv + m][32*ks + 8*qd];
            #pragma unroll
            for (int nt = 0; nt < 4; ++nt) {
                h8 bb = *(const h8*)&Bs[cur][16*nt + m][32*ks + 8*qd];
                acc[nt] = mfma16(a, bb, acc[nt]);
            }
        }
        if (kt < 7) {
            const int alt = cur ^ 1;
            const int st = (kt + 1) % 3;
            *(h8*)&Bs[alt][br][bc0]     = b0p[st];
            *(h8*)&Bs[alt][br][bc0 + 8] = b1p[st];
            #pragma unroll
            for (int i = 0; i < 8; ++i) As[alt][lg*16 + i][kcol]     = g0p[st][i];
            #pragma unroll
            for (int i = 0; i < 8; ++i) As[alt][lg*16 + 8 + i][kcol] = g1p[st][i];
            __syncthreads();
        }
    }

    #pragma unroll
    for (int nt = 0; nt < 4; ++nt)
        #pragma unroll
        for (int r = 0; r < 4; ++r) {
            int b = 4*qd + r;
            qw[((size_t)(b*HH + h)*LL + l0 + wv)*EE + 16*nt + m] = (_Float16)acc[nt][r];
        }
}

// ---------------- K1: fused qkv + qshuf, XCD-aware swizzle ---------------
__global__ __launch_bounds__(256) void k_qkv_qshuf(
    const _Float16* __restrict__ x16, const _Float16* __restrict__ xT,
    const int* __restrict__ perms, const _Float16* __restrict__ WT,
    _Float16* __restrict__ qw, _Float16* __restrict__ kw, _Float16* __restrict__ vw)
{
    __shared__ __align__(16) _Float16 smem[4*128*72];   // 73728 B
    const int bx = blockIdx.x;
    const int lx = (bx & 7) * 368 + (bx >> 3);          // XCD-contiguous logical id
    const int g = lx / 23, pos = lx % 23;
    if (pos < 9) {
        const int qid = g*9 + pos;            // [0,1152)
        qkv_body(qid % 9, (qid / 9) * 128, x16, WT, qw, kw, vw, smem);
    } else {
        const int sid = g*14 + (pos - 9);     // [0,1792)
        qshuf_body((sid & 255) * 4, (sid >> 8) + 1, xT, perms, WT, qw, smem);
    }
}

// ---------------- K3: attention v9 — QBLK=512, 1024 threads --------------
// attn's remaining cost is K/V re-read amplification (4 blocks per bh x
// 256 KB = 134 MB). QBLK 256->512 halves that (2 blocks/bh). Per-wave
// structure identical (16 waves x 32 q-rows); staging wave-specialized:
// waves 0-7 stage K, waves 8-15 stage V (half the per-thread staging work).
// 4-buffer / 1-barrier-per-2-tiles scheme unchanged; LDS 64 KB; 256 blocks
// = 1/CU, 16 waves/CU as before.
__global__ __launch_bounds__(1024, 4) void k_attn(
    const _Float16* __restrict__ qw, const _Float16* __restrict__ kw,
    const _Float16* __restrict__ vw, _Float16* __restrict__ oa)
{
    const int bh = blockIdx.x;
    const int l0 = blockIdx.y * 512;
    const int b = bh >> 3, h = bh & 7;
    const _Float16* qb = qw + ((size_t)bh*LL + l0)*EE;
    const _Float16* kb = kw + (size_t)bh*LL*EE;
    const _Float16* vb = vw + (size_t)bh*LL*EE;

    __shared__ __align__(16) _Float16 KsF[4][64*64];
    __shared__ __align__(16) _Float16 VtsF[4][64*64];

    const int t = threadIdx.x;
    const int wv = t >> 6, lane = t & 63;
    const int m = lane & 15, qd = lane >> 4;
    const int m7 = m & 7;
    const int qdp = ((qd & 1) << 1) | (qd >> 1);   // chunk perm from permlane build
    const bool isK = (t < 512);
    const int u = t & 511;
    const int krow = u >> 3, c0 = u & 7;           // K staging half: 1 h8/thread
    const int vkey = u & 63, vec = u >> 6;         // V staging half
    const int vhi = vkey >> 3, vlo = vkey & 7;

    h8 qa[2][2];
    #pragma unroll
    for (int mt = 0; mt < 2; ++mt)
        #pragma unroll
        for (int ks = 0; ks < 2; ++ks)
            qa[mt][ks] = *(const h8*)(qb + (size_t)(32*wv + 16*mt + m)*EE + 32*ks + 8*qd);

    f4 oacc[2][4] = {};
    f4 lpacc[2] = {};
    h8 ones;
    #pragma unroll
    for (int i = 0; i < 8; ++i) ones[i] = (_Float16)1.f;

    auto loadKV = [&](int kt) -> h8 {
        if (isK) return *(const h8*)(kb + (size_t)(kt*64 + krow)*EE + 8*c0);
        else     return *(const h8*)(vb + (size_t)(kt*64 + vkey)*EE + 8*vec);
    };
    auto stageKV = [&](int buf, h8 r) {
        if (isK) {
            *(h8*)&KsF[buf][(krow<<6) + 8*(c0 ^ (krow & 7))] = r;
        } else {
            #pragma unroll
            for (int i = 0; i < 8; ++i)
                VtsF[buf][((8*vec + i)<<6) + 8*(vhi ^ i) + vlo] = r[i];
        }
    };
    auto compute = [&](int buf) {
        f4 sacc[2][4] = {};
        __builtin_amdgcn_s_setprio(1);
        #pragma unroll
        for (int ks = 0; ks < 2; ++ks)
            #pragma unroll
            for (int nt = 0; nt < 4; ++nt) {
                h8 kf = *(const h8*)&KsF[buf][((16*nt + m)<<6) + 8*((4*ks + qd) ^ m7)];
                sacc[0][nt] = mfma16(kf, qa[0][ks], sacc[0][nt]);
                sacc[1][nt] = mfma16(kf, qa[1][ks], sacc[1][nt]);
            }
        __builtin_amdgcn_s_setprio(0);

        unsigned E[2][4][2];
        #pragma unroll
        for (int mt = 0; mt < 2; ++mt)
            #pragma unroll
            for (int nt = 0; nt < 4; ++nt) {
                float e0 = __builtin_amdgcn_exp2f(sacc[mt][nt][0]);
                float e1 = __builtin_amdgcn_exp2f(sacc[mt][nt][1]);
                float e2 = __builtin_amdgcn_exp2f(sacc[mt][nt][2]);
                float e3 = __builtin_amdgcn_exp2f(sacc[mt][nt][3]);
                E[mt][nt][0] = __builtin_bit_cast(unsigned, __builtin_amdgcn_cvt_pkrtz(e0, e1));
                E[mt][nt][1] = __builtin_bit_cast(unsigned, __builtin_amdgcn_cvt_pkrtz(e2, e3));
            }

        h8 pa[2][2];
        #pragma unroll
        for (int mt = 0; mt < 2; ++mt)
            #pragma unroll
            for (int ks = 0; ks < 2; ++ks) {
                auto xx = __builtin_amdgcn_permlane16_swap(E[mt][2*ks][0], E[mt][2*ks+1][0], false, false);
                auto yy = __builtin_amdgcn_permlane16_swap(E[mt][2*ks][1], E[mt][2*ks+1][1], false, false);
                i4 pw;
                pw[0] = (int)xx[0]; pw[1] = (int)yy[0]; pw[2] = (int)xx[1]; pw[3] = (int)yy[1];
                pa[mt][ks] = __builtin_bit_cast(h8, pw);
            }

        __builtin_amdgcn_s_setprio(1);
        #pragma unroll
        for (int ks = 0; ks < 2; ++ks) {
            #pragma unroll
            for (int nt = 0; nt < 4; ++nt) {
                h8 vf = *(const h8*)&VtsF[buf][((16*nt + m)<<6) + 8*((4*ks + qdp) ^ m7)];
                oacc[0][nt] = mfma16(pa[0][ks], vf, oacc[0][nt]);
                oacc[1][nt] = mfma16(pa[1][ks], vf, oacc[1][nt]);
            }
            lpacc[0] = mfma16(pa[0][ks], ones, lpacc[0]);
            lpacc[1] = mfma16(pa[1][ks], ones, lpacc[1]);
        }
        __builtin_amdgcn_s_setprio(0);
    };

    // prologue: tiles 0,1 into buffers 0,1
    {
        h8 r0 = loadKV(0), r1 = loadKV(1);
        stageKV(0, r0);
        stageKV(1, r1);
    }
    __syncthreads();

    #pragma unroll
    for (int j = 0; j < 8; ++j) {
        h8 ra, rc;
        if (j < 7) {
            ra = loadKV(2*j + 2);
            rc = loadKV(2*j + 3);
        }
        compute((2*j) & 3);
        if (j < 7) stageKV((2*j + 2) & 3, ra);
        compute((2*j + 1) & 3);
        if (j < 7) {
            stageKV((2*j + 3) & 3, rc);
            __syncthreads();
        }
    }

    _Float16* ob = oa + ((size_t)(b*LL + l0))*(HH*EE) + h*EE;
    #pragma unroll
    for (int mt = 0; mt < 2; ++mt)
        #pragma unroll
        for (int r = 0; r < 4; ++r) {
            const float inv = __builtin_amdgcn_rcpf(lpacc[mt][r]);
            #pragma unroll
            for (int nt = 0; nt < 4; ++nt) {
                int row = 32*wv + 16*mt + 4*qd + r;
                ob[(size_t)row*(HH*EE) + 16*nt + m] = (_Float16)(oacc[mt][nt][r] * inv);
            }
        }
}

// ---------------- K4: output projection, XCD-aware swizzle ---------------
__global__ __launch_bounds__(256) void k_oproj(
    const _Float16* __restrict__ oa, const _Float16* __restrict__ Wo16,
    const float* __restrict__ bo, float* __restrict__ out)
{
    const int lid = ((int)blockIdx.x & 7) * 64 + ((int)blockIdx.x >> 3);
    const int y  = lid & 3;
    const int r0 = (lid >> 2) * 128;

    __shared__ __align__(16) _Float16 As[2][128][72];
    __shared__ __align__(16) _Float16 Bs[2][128][72];

    const int t = threadIdx.x;
    const int wv = t >> 6, lane = t & 63;
    const int m = lane & 15, qd = lane >> 4;
    const int sr = t >> 1, sc0 = (t & 1) * 32;

    const _Float16* ax = oa   + (size_t)(r0 + sr)*DD + sc0;
    const _Float16* bx = Wo16 + (size_t)(y*128 + sr)*DD + sc0;

    #pragma unroll
    for (int c = 0; c < 4; ++c) {
        *(h8*)&As[0][sr][sc0 + 8*c] = *(const h8*)(ax + 8*c);
        *(h8*)&Bs[0][sr][sc0 + 8*c] = *(const h8*)(bx + 8*c);
    }
    __syncthreads();

    f4 acc[2][8] = {};
    int cur = 0;
    for (int kt = 0; kt < 8; ++kt) {
        const int alt = cur ^ 1;
        h8 an[4], bn[4];
        if (kt < 7) {
            const _Float16* a2 = ax + (kt+1)*64;
            const _Float16* b2 = bx + (kt+1)*64;
            #pragma unroll
            for (int c = 0; c < 4; ++c) {
                an[c] = *(const h8*)(a2 + 8*c);
                bn[c] = *(const h8*)(b2 + 8*c);
            }
        }
        #pragma unroll
        for (int ks = 0; ks < 2; ++ks) {
            h8 a0 = *(const h8*)&As[cur][32*wv +  0 + m][32*ks + 8*qd];
            h8 a1 = *(const h8*)&As[cur][32*wv + 16 + m][32*ks + 8*qd];
            #pragma unroll
            for (int nt = 0; nt < 8; ++nt) {
                h8 bb = *(const h8*)&Bs[cur][16*nt + m][32*ks + 8*qd];
                acc[0][nt] = mfma16(a0, bb, acc[0][nt]);
                acc[1][nt] = mfma16(a1, bb, acc[1][nt]);
            }
        }
        if (kt < 7) {
            #pragma unroll
            for (int c = 0; c < 4; ++c) {
                *(h8*)&As[alt][sr][sc0 + 8*c] = an[c];
                *(h8*)&Bs[alt][sr][sc0 + 8*c] = bn[c];
            }
            __syncthreads();
            cur = alt;
        }
    }

    #pragma unroll
    for (int nt = 0; nt < 8; ++nt) {
        const int col = y*128 + 16*nt + m;
        const float bias = bo[col];
        #pragma unroll
        for (int mt = 0; mt < 2; ++mt)
            #pragma unroll
            for (int r = 0; r < 4; ++r) {
                int row = 32*wv + 16*mt + 4*qd + r;
                out[(size_t)(r0 + row)*DD + col] = acc[mt][nt][r] + bias;
            }
    }
}

extern "C" void kernel_launch(void* const* d_in, const int* in_sizes, int n_in,
                              void* d_out, int out_size, void* d_ws, size_t ws_size,
                              hipStream_t stream)
{
    const float* x  = (const float*)d_in[0];
    const int*   pm = (const int*)d_in[1];
    const float* Wq = (const float*)d_in[2];
    const float* Wk = (const float*)d_in[3];
    const float* Wv = (const float*)d_in[4];
    const float* Wo = (const float*)d_in[5];
    const float* bo = (const float*)d_in[6];
    float* out = (float*)d_out;

    const size_t QS = (size_t)BB * HH * LL * EE;   // 8388608 elements (16.78 MB)
    // d_out (33.55 MB) hosts x16 and q, both dead before k_oproj writes out.
    _Float16* x16  = (_Float16*)d_out;
    _Float16* q    = (_Float16*)d_out + QS;
    _Float16* k    = (_Float16*)d_ws;
    _Float16* v    = k + QS;
    _Float16* oaw  = v + QS;
    _Float16* xT   = oaw;              // alias: dead before k_attn writes oaw
    _Float16* WT   = oaw + QS;
    _Float16* Wo16 = WT + (size_t)24*64*DD;

    k_prep_all <<<dim3(2048 + 192 + 256), 256, 0, stream>>>(
        x, Wq, Wk, Wv, Wo, xT, x16, WT, Wo16);
    k_qkv_qshuf<<<dim3(2944),          256,  0, stream>>>(x16, xT, pm, WT, q, k, v);
    k_attn     <<<dim3(BB*HH, LL/512), 1024, 0, stream>>>(q, k, v, oaw);
    k_oproj    <<<dim3(512),           256,  0, stream>>>(oaw, Wo16, bo, out);
}